// Round 6
// baseline (456.835 us; speedup 1.0000x reference)
//
#include <hip/hip_runtime.h>
#include <hip/hip_bf16.h>
#include <math.h>

#define NN 1024
#define CC 128
#define C2 64
#define KK 16

// ---------------- K0: A = M^T M, f32, ascending-r fmaf chain ---------------
// Replicates OpenBLAS sgemm: per output, k-loop sequential single-acc FMA.
__global__ __launch_bounds__(256) void buildA(const float* __restrict__ M,
                                              float* __restrict__ A) {
    const int e = blockIdx.x * 256 + threadIdx.x;    // 4096 entries
    const int c = e >> 6, d = e & 63;
    float acc = 0.f;
    #pragma unroll 8
    for (int r = 0; r < C2; ++r)
        acc = fmaf(M[r * C2 + c], M[r * C2 + d], acc);
    A[e] = acc;                                      // A[c][d] row-major
}

// ---------------- K1: projections + logmap, all f32 ------------------------
// pm/ps[bn*64+d] = sign(x)*logf(|x|+1e-10), x = ascending-c fmaf chain
// (replicates np f32 sgemm + np.log f32).
__global__ __launch_bounds__(128) void proj(
        const float* __restrict__ X,
        const float* __restrict__ Wm,
        const float* __restrict__ Ws,
        float* __restrict__ pm,
        float* __restrict__ ps) {
    const int bn = blockIdx.x;           // b*1024 + n
    const int b  = bn >> 10;
    const int n  = bn & (NN - 1);
    const int t  = threadIdx.x;          // 0..127

    __shared__ float xv[CC];
    xv[t] = X[b * CC * NN + t * NN + n]; // exact f32 bits
    __syncthreads();

    const int d = t & (C2 - 1);
    const float* wr = ((t < C2) ? Wm : Ws) + d * CC;
    float acc = 0.f;
    #pragma unroll
    for (int c = 0; c < CC; ++c)
        acc = fmaf(wr[c], xv[c], acc);   // sequential k-order, single acc

    float a = __fadd_rn(fabsf(acc), 1e-10f);
    float l = logf(a);
    float r = (acc > 0.f) ? l : ((acc < 0.f) ? -l : 0.f);
    ((t < C2) ? pm : ps)[bn * C2 + d] = r;
}

// ---------------- K2: pairwise diff (np-f32 op-order) + top-16 -------------
// One block per (b,i), 256 threads, each thread 4 j's.
//   s_c   = 1/(1+expf(ps_c - pm_c))                 (naive expit, f32)
//   w_d   = sum_c fmaf(s_c, A[c][d])  ascending c   (tensordot sgemm order)
//   t_d   = w_d * s_d (separate rounding)
//   dis2  = numpy pairwise-8 sum over d
//   diff  = 1/(1+expf(sqrtf(dis2)))
// Rank by (diff desc, index asc) — mirrors np argsort-stable on f32 diff.
__global__ __launch_bounds__(256, 1) void pair_topk(
        const float* __restrict__ pm,
        const float* __restrict__ ps,
        const float* __restrict__ A,
        float* __restrict__ out) {
    const int bi  = blockIdx.x;          // b*1024 + i
    const int b   = bi >> 10;
    const int i   = bi & (NN - 1);
    const int tid = threadIdx.x;

    __shared__ float pm_s[C2];
    __shared__ float s_lds[C2][256];     // 64 KB; column tid is thread-private
    __shared__ float diff_lds[NN];

    if (tid < C2) pm_s[tid] = pm[bi * C2 + tid];
    __syncthreads();

    const float* psb = ps + b * NN * C2;

    #pragma unroll 1
    for (int it = 0; it < 4; ++it) {
        const int j = it * 256 + tid;
        const float4* psr = (const float4*)(psb + j * C2);

        // ---- s_c -> s_lds[c][tid] (static indices; no cross-thread use) ----
        #pragma unroll
        for (int q = 0; q < 16; ++q) {
            float4 v = psr[q];
            float e0 = expf(v.x - pm_s[4*q+0]);
            float e1 = expf(v.y - pm_s[4*q+1]);
            float e2 = expf(v.z - pm_s[4*q+2]);
            float e3 = expf(v.w - pm_s[4*q+3]);
            s_lds[4*q+0][tid] = 1.0f / __fadd_rn(1.0f, e0);
            s_lds[4*q+1][tid] = 1.0f / __fadd_rn(1.0f, e1);
            s_lds[4*q+2][tid] = 1.0f / __fadd_rn(1.0f, e2);
            s_lds[4*q+3][tid] = 1.0f / __fadd_rn(1.0f, e3);
        }

        // ---- w_d = sum_c s_c * A[c][d], ascending c, fmaf ----
        float w[C2];
        #pragma unroll
        for (int d = 0; d < C2; ++d) w[d] = 0.f;

        #pragma unroll 1
        for (int c = 0; c < C2; ++c) {
            float sc = s_lds[c][tid];
            const int off = __builtin_amdgcn_readfirstlane(c * C2); // force SGPR
            const float* Ar = A + off;       // wave-uniform -> s_load
            #pragma unroll
            for (int d = 0; d < C2; ++d)
                w[d] = fmaf(sc, Ar[d], w[d]);
        }

        // ---- dis2 = numpy pairwise-8 over t_d = w_d * s_d ----
        float r8[8];
        #pragma unroll
        for (int q = 0; q < 8; ++q)
            r8[q] = __fmul_rn(w[q], s_lds[q][tid]);
        #pragma unroll
        for (int blk = 1; blk < 8; ++blk) {
            #pragma unroll
            for (int q = 0; q < 8; ++q)
                r8[q] = __fadd_rn(r8[q],
                        __fmul_rn(w[8*blk+q], s_lds[8*blk+q][tid]));
        }
        float dis2 = __fadd_rn(
            __fadd_rn(__fadd_rn(r8[0], r8[1]), __fadd_rn(r8[2], r8[3])),
            __fadd_rn(__fadd_rn(r8[4], r8[5]), __fadd_rn(r8[6], r8[7])));

        float disf = sqrtf(dis2);                    // correctly rounded
        float ee = expf(disf);
        diff_lds[j] = 1.0f / __fadd_rn(1.0f, ee);    // sigmoid(-dis)
    }
    __syncthreads();

    if (tid >= 64) return;                           // wave 0; no barriers below

    // ---- top-16: argmax passes on f32 diff (desc, index asc) ----
    float v[16];
    #pragma unroll
    for (int q = 0; q < 16; ++q) v[q] = diff_lds[q * 64 + tid];

    const int obase = b * (NN * KK) + i * KK;        // index chunk (f32)
    const int vbase = 2 * NN * KK + obase;           // value chunk (f32)

    #pragma unroll 1
    for (int k = 0; k < KK; ++k) {
        float bv = v[0];
        int bidx = tid;
        #pragma unroll
        for (int q = 1; q < 16; ++q) {
            float cv = v[q];
            int ci = q * 64 + tid;
            bool better = (cv > bv) || (cv == bv && ci < bidx);
            bv = better ? cv : bv;
            bidx = better ? ci : bidx;
        }
        #pragma unroll
        for (int st = 0; st < 6; ++st) {
            int msk = 1 << st;
            float ov = __shfl_xor(bv, msk, 64);
            int oi = __shfl_xor(bidx, msk, 64);
            bool better = (ov > bv) || (ov == bv && oi < bidx);
            bv = better ? ov : bv;
            bidx = better ? oi : bidx;
        }
        #pragma unroll
        for (int q = 0; q < 16; ++q)
            if (bidx == q * 64 + tid) v[q] = -1.0f;  // diff > 0 always
        if (tid == 0) {
            out[obase + k] = (float)bidx;
            out[vbase + k] = -bv;                    // value = -topk(diff)
        }
    }
}

extern "C" void kernel_launch(void* const* d_in, const int* in_sizes, int n_in,
                              void* d_out, int out_size, void* d_ws, size_t ws_size,
                              hipStream_t stream) {
    const float* X  = (const float*)d_in[0];
    const float* Wm = (const float*)d_in[1];
    const float* Ws = (const float*)d_in[2];
    const float* M  = (const float*)d_in[3];

    float* A  = (float*)d_ws;            // 4096 f   (16 KB)
    float* pm = A + C2 * C2;             // 131072 f (512 KB)
    float* ps = pm + 2 * NN * C2;        // 131072 f (512 KB)  total ~1.02 MB
    float* out = (float*)d_out;          // f32: [idx 32768][val 32768]

    hipLaunchKernelGGL(buildA, dim3(16), dim3(256), 0, stream, M, A);
    hipLaunchKernelGGL(proj, dim3(2 * NN), dim3(128), 0, stream,
                       X, Wm, Ws, pm, ps);
    hipLaunchKernelGGL(pair_topk, dim3(2 * NN), dim3(256), 0, stream,
                       pm, ps, A, out);
}

// Round 7
// 378.102 us; speedup vs baseline: 1.2082x; 1.2082x over previous
//
#include <hip/hip_runtime.h>
#include <hip/hip_bf16.h>
#include <math.h>

#define NN 1024
#define CC 128
#define C2 64
#define KK 16
#define NCAND 24

#if __has_builtin(__builtin_amdgcn_exp2f)
#define EXP2F(x) __builtin_amdgcn_exp2f(x)
#else
#define EXP2F(x) exp2f(x)
#endif
#define LOG2E 1.4426950408889634f

__device__ __forceinline__ float fast_rcp(float x) {
    return __builtin_amdgcn_rcpf(x);
}

// LDS write->read visibility within one wave (lockstep): wait LDS ops, pin order.
#define LDS_FENCE() do { \
    asm volatile("s_waitcnt lgkmcnt(0)" ::: "memory"); \
    __builtin_amdgcn_sched_barrier(0); } while (0)

// ---------------- K0: A = M^T M, f32, ascending-r fmaf chain (np-exact) ----
__global__ __launch_bounds__(256) void buildA(const float* __restrict__ M,
                                              float* __restrict__ A) {
    const int e = blockIdx.x * 256 + threadIdx.x;    // 4096 entries
    const int c = e >> 6, d = e & 63;
    float acc = 0.f;
    #pragma unroll 8
    for (int r = 0; r < C2; ++r)
        acc = fmaf(M[r * C2 + c], M[r * C2 + d], acc);
    A[e] = acc;                                      // A[c][d] row-major
}

// ---------------- K1: projections + logmap, f32 (np-exact) -----------------
__global__ __launch_bounds__(128) void proj(
        const float* __restrict__ X,
        const float* __restrict__ Wm,
        const float* __restrict__ Ws,
        float* __restrict__ pm,
        float* __restrict__ ps) {
    const int bn = blockIdx.x;           // b*1024 + n
    const int b  = bn >> 10;
    const int n  = bn & (NN - 1);
    const int t  = threadIdx.x;          // 0..127

    __shared__ float xv[CC];
    xv[t] = X[b * CC * NN + t * NN + n];
    __syncthreads();

    const int d = t & (C2 - 1);
    const float* wr = ((t < C2) ? Wm : Ws) + d * CC;
    float acc = 0.f;
    #pragma unroll
    for (int c = 0; c < CC; ++c)
        acc = fmaf(wr[c], xv[c], acc);   // sequential k-order, single acc

    float a = __fadd_rn(fabsf(acc), 1e-10f);
    float l = logf(a);
    float r = (acc > 0.f) ? l : ((acc < 0.f) ? -l : 0.f);
    ((t < C2) ? pm : ps)[bn * C2 + d] = r;
}

// ---------------- K2: fast candidate pass + np-exact re-rank ---------------
// One block per (b,i), 256 threads.
//  A: fast f32 u-form dis2 for all 1024 j (regs only, any op order — proxy)
//  B: wave0 picks 24 smallest-dis2 candidates (superset of np top-16)
//  C: 4 waves rescore candidates with R6's EXACT np-f32 op sequence
//  F: wave0 top-16 on exact diff (desc, index asc) -> out
__global__ __launch_bounds__(256, 4) void pair_topk(
        const float* __restrict__ pm,
        const float* __restrict__ ps,
        const float* __restrict__ Mf,
        const float* __restrict__ A,
        float* __restrict__ out) {
    const int bi  = blockIdx.x;          // b*1024 + i
    const int b   = bi >> 10;
    const int i   = bi & (NN - 1);
    const int tid = threadIdx.x;

    __shared__ float pm_lds[C2];
    __shared__ float d2_lds[NN];
    __shared__ int   cand_lds[NCAND];
    __shared__ float cdiff_lds[NCAND];
    __shared__ float sC[4][C2];
    __shared__ float tC[4][C2];
    __shared__ float r8C[4][8];

    if (tid < C2) pm_lds[tid] = pm[bi * C2 + tid];   // exact f32 pm row
    __syncthreads();

    const float* psb = ps + b * NN * C2;

    // ---- Phase A: fast f32 dis2 = |M s|^2 (registers only) ----
    const float4* pm4 = (const float4*)pm_lds;
    #pragma unroll 1
    for (int it = 0; it < 4; ++it) {
        const int j = it * 256 + tid;
        const float4* psr = (const float4*)(psb + j * C2);

        float s[C2];
        #pragma unroll
        for (int q = 0; q < C2 / 4; ++q) {
            float4 v  = psr[q];
            float4 pv = pm4[q];                      // LDS broadcast b128
            s[4*q+0] = fast_rcp(1.0f + EXP2F((v.x - pv.x) * LOG2E));
            s[4*q+1] = fast_rcp(1.0f + EXP2F((v.y - pv.y) * LOG2E));
            s[4*q+2] = fast_rcp(1.0f + EXP2F((v.z - pv.z) * LOG2E));
            s[4*q+3] = fast_rcp(1.0f + EXP2F((v.w - pv.w) * LOG2E));
        }

        float dis2 = 0.f;
        #pragma unroll 2
        for (int r = 0; r < C2; ++r) {
            const float* Mr = Mf + r * C2;           // wave-uniform -> s_load
            float u = 0.f;
            #pragma unroll
            for (int c = 0; c < C2; ++c) u = fmaf(Mr[c], s[c], u);
            dis2 = fmaf(u, u, dis2);
        }
        d2_lds[j] = dis2;                            // rank proxy (asc == diff desc)
    }
    __syncthreads();

    // ---- Phase B: 24 smallest-dis2 candidate indices (wave 0) ----
    if (tid < 64) {
        float v[16];
        #pragma unroll
        for (int q = 0; q < 16; ++q) v[q] = d2_lds[q * 64 + tid];

        int myidx = 1 << 20;
        #pragma unroll 1
        for (int k = 0; k < NCAND; ++k) {
            float bv = v[0];
            int bidx = tid;
            #pragma unroll
            for (int q = 1; q < 16; ++q) {
                float cv = v[q];
                int ci = q * 64 + tid;
                bool better = (cv < bv) || (cv == bv && ci < bidx);
                bv = better ? cv : bv;
                bidx = better ? ci : bidx;
            }
            #pragma unroll
            for (int st = 0; st < 6; ++st) {
                int msk = 1 << st;
                float ov = __shfl_xor(bv, msk, 64);
                int oi = __shfl_xor(bidx, msk, 64);
                bool better = (ov < bv) || (ov == bv && oi < bidx);
                bv = better ? ov : bv;
                bidx = better ? oi : bidx;
            }
            #pragma unroll
            for (int q = 0; q < 16; ++q)
                if (bidx == q * 64 + tid) v[q] = 3.4e38f;
            if (tid == k) myidx = bidx;
        }
        if (tid < NCAND) cand_lds[tid] = myidx;
    }
    __syncthreads();

    // ---- Phase C: np-exact rescore (R6's bit-exact op order) ----
    {
        const int wv = tid >> 6, lane = tid & 63;
        #pragma unroll 1
        for (int t = wv; t < NCAND; t += 4) {
            const int j = cand_lds[t];
            // s_c = 1/(1+expf(ps_c - pm_c)), lane = c
            float psc = psb[(long)j * C2 + lane];
            float e = expf(psc - pm_lds[lane]);
            float s_own = 1.0f / __fadd_rn(1.0f, e);
            sC[wv][lane] = s_own;
            LDS_FENCE();
            // w_d = sum_c s_c * A[c][d], ascending c, single fmaf acc; lane = d
            float wd = 0.f;
            #pragma unroll 4
            for (int c = 0; c < C2; ++c)
                wd = fmaf(sC[wv][c], A[c * C2 + lane], wd);
            // t_d = w_d * s_d (separate rounding)
            tC[wv][lane] = __fmul_rn(wd, s_own);
            LDS_FENCE();
            // numpy pairwise-8 partial sums
            if (lane < 8) {
                float r8 = tC[wv][lane];
                #pragma unroll
                for (int blk = 1; blk < 8; ++blk)
                    r8 = __fadd_rn(r8, tC[wv][8 * blk + lane]);
                r8C[wv][lane] = r8;
            }
            LDS_FENCE();
            if (lane == 0) {
                float dis2 = __fadd_rn(
                    __fadd_rn(__fadd_rn(r8C[wv][0], r8C[wv][1]),
                              __fadd_rn(r8C[wv][2], r8C[wv][3])),
                    __fadd_rn(__fadd_rn(r8C[wv][4], r8C[wv][5]),
                              __fadd_rn(r8C[wv][6], r8C[wv][7])));
                float disf = sqrtf(dis2);
                float ee = expf(disf);
                cdiff_lds[t] = 1.0f / __fadd_rn(1.0f, ee);  // sigmoid(-dis)
            }
            LDS_FENCE();
        }
    }
    __syncthreads();

    // ---- Final: top-16 over 24 exact diffs (desc, index asc), wave 0 ----
    if (tid < 64) {
        float myd = (tid < NCAND) ? cdiff_lds[tid] : -2.0f;
        int myj = (tid < NCAND) ? cand_lds[tid] : (1 << 20);

        const int obase = b * (NN * KK) + i * KK;    // index chunk (f32)
        const int vbase = 2 * NN * KK + obase;       // value chunk (f32)

        #pragma unroll 1
        for (int k = 0; k < KK; ++k) {
            float bd = myd;
            int bj = myj;
            #pragma unroll
            for (int st = 0; st < 6; ++st) {
                int msk = 1 << st;
                float od = __shfl_xor(bd, msk, 64);
                int oj = __shfl_xor(bj, msk, 64);
                bool better = (od > bd) || (od == bd && oj < bj);
                bd = better ? od : bd;
                bj = better ? oj : bj;
            }
            if (myj == bj) myd = -2.0f;              // candidate j's unique
            if (tid == 0) {
                out[obase + k] = (float)bj;
                out[vbase + k] = -bd;                // value = -topk(diff)
            }
        }
    }
}

extern "C" void kernel_launch(void* const* d_in, const int* in_sizes, int n_in,
                              void* d_out, int out_size, void* d_ws, size_t ws_size,
                              hipStream_t stream) {
    const float* X  = (const float*)d_in[0];
    const float* Wm = (const float*)d_in[1];
    const float* Ws = (const float*)d_in[2];
    const float* M  = (const float*)d_in[3];

    float* A  = (float*)d_ws;            // 4096 f   (16 KB)
    float* pm = A + C2 * C2;             // 131072 f (512 KB)
    float* ps = pm + 2 * NN * C2;        // 131072 f (512 KB)
    float* out = (float*)d_out;          // f32: [idx 32768][val 32768]

    hipLaunchKernelGGL(buildA, dim3(16), dim3(256), 0, stream, M, A);
    hipLaunchKernelGGL(proj, dim3(2 * NN), dim3(128), 0, stream,
                       X, Wm, Ws, pm, ps);
    hipLaunchKernelGGL(pair_topk, dim3(2 * NN), dim3(256), 0, stream,
                       pm, ps, M, A, out);
}

// Round 8
// 351.094 us; speedup vs baseline: 1.3012x; 1.0769x over previous
//
#include <hip/hip_runtime.h>
#include <hip/hip_bf16.h>
#include <math.h>

#define NN 1024
#define CC 128
#define C2 64
#define KK 16
#define NCAND 24

#if __has_builtin(__builtin_amdgcn_exp2f)
#define EXP2F(x) __builtin_amdgcn_exp2f(x)
#else
#define EXP2F(x) exp2f(x)
#endif
#define LOG2E 1.4426950408889634f

__device__ __forceinline__ float fast_rcp(float x) {
    return __builtin_amdgcn_rcpf(x);
}

// LDS write->read visibility within one wave (lockstep): wait LDS ops, pin order.
#define LDS_FENCE() do { \
    asm volatile("s_waitcnt lgkmcnt(0)" ::: "memory"); \
    __builtin_amdgcn_sched_barrier(0); } while (0)

// ---------------- K0: A = M^T M, f32, ascending-r fmaf chain (np-exact) ----
__global__ __launch_bounds__(256) void buildA(const float* __restrict__ M,
                                              float* __restrict__ A) {
    const int e = blockIdx.x * 256 + threadIdx.x;    // 4096 entries
    const int c = e >> 6, d = e & 63;
    float acc = 0.f;
    #pragma unroll 8
    for (int r = 0; r < C2; ++r)
        acc = fmaf(M[r * C2 + c], M[r * C2 + d], acc);
    A[e] = acc;                                      // A[c][d] row-major
}

// ---------------- K1: projections + logmap, f32 (np-exact) -----------------
__global__ __launch_bounds__(128) void proj(
        const float* __restrict__ X,
        const float* __restrict__ Wm,
        const float* __restrict__ Ws,
        float* __restrict__ pm,
        float* __restrict__ ps) {
    const int bn = blockIdx.x;           // b*1024 + n
    const int b  = bn >> 10;
    const int n  = bn & (NN - 1);
    const int t  = threadIdx.x;          // 0..127

    __shared__ float xv[CC];
    xv[t] = X[b * CC * NN + t * NN + n];
    __syncthreads();

    const int d = t & (C2 - 1);
    const float* wr = ((t < C2) ? Wm : Ws) + d * CC;
    float acc = 0.f;
    #pragma unroll
    for (int c = 0; c < CC; ++c)
        acc = fmaf(wr[c], xv[c], acc);   // sequential k-order, single acc

    float a = __fadd_rn(fabsf(acc), 1e-10f);
    float l = logf(a);
    float r = (acc > 0.f) ? l : ((acc < 0.f) ? -l : 0.f);
    ((t < C2) ? pm : ps)[bn * C2 + d] = r;
}

// ---------------- K2: fast candidate pass + np-exact re-rank ---------------
// One block per (b,i), 256 threads.
//  A: fast f32 u-form dis2 for all 1024 j (regs only, any op order — proxy)
//  B: wave0 picks 24 smallest-dis2 candidates (superset of np top-16)
//  C: 4 waves rescore candidates with R6's EXACT np-f32 op sequence
//  F: wave0 top-16 on exact diff (desc, index asc) -> out
// launch_bounds (256,2): natural VGPR use ~100 (s[64] live set) -> NO SPILL.
// R7's (256,4) forced a 64-VGPR cap -> 56 MB scratch traffic per dispatch.
__global__ __launch_bounds__(256, 2) void pair_topk(
        const float* __restrict__ pm,
        const float* __restrict__ ps,
        const float* __restrict__ Mf,
        const float* __restrict__ A,
        float* __restrict__ out) {
    const int bi  = blockIdx.x;          // b*1024 + i
    const int b   = bi >> 10;
    const int i   = bi & (NN - 1);
    const int tid = threadIdx.x;

    __shared__ float pm_lds[C2];
    __shared__ float d2_lds[NN];
    __shared__ int   cand_lds[NCAND];
    __shared__ float cdiff_lds[NCAND];
    __shared__ float sC[4][C2];
    __shared__ float tC[4][C2];
    __shared__ float r8C[4][8];

    if (tid < C2) pm_lds[tid] = pm[bi * C2 + tid];   // exact f32 pm row
    __syncthreads();

    const float* psb = ps + b * NN * C2;

    // ---- Phase A: fast f32 dis2 = |M s|^2 (registers only) ----
    const float4* pm4 = (const float4*)pm_lds;
    #pragma unroll 1
    for (int it = 0; it < 4; ++it) {
        const int j = it * 256 + tid;
        const float4* psr = (const float4*)(psb + j * C2);

        float s[C2];
        #pragma unroll
        for (int q = 0; q < C2 / 4; ++q) {
            float4 v  = psr[q];
            float4 pv = pm4[q];                      // LDS broadcast b128
            s[4*q+0] = fast_rcp(1.0f + EXP2F((v.x - pv.x) * LOG2E));
            s[4*q+1] = fast_rcp(1.0f + EXP2F((v.y - pv.y) * LOG2E));
            s[4*q+2] = fast_rcp(1.0f + EXP2F((v.z - pv.z) * LOG2E));
            s[4*q+3] = fast_rcp(1.0f + EXP2F((v.w - pv.w) * LOG2E));
        }

        float dis2 = 0.f;
        #pragma unroll 2
        for (int r = 0; r < C2; ++r) {
            const float* Mr = Mf + r * C2;           // wave-uniform -> s_load
            float u = 0.f;
            #pragma unroll
            for (int c = 0; c < C2; ++c) u = fmaf(Mr[c], s[c], u);
            dis2 = fmaf(u, u, dis2);
        }
        d2_lds[j] = dis2;                            // rank proxy (asc == diff desc)
    }
    __syncthreads();

    // ---- Phase B: 24 smallest-dis2 candidate indices (wave 0) ----
    if (tid < 64) {
        float v[16];
        #pragma unroll
        for (int q = 0; q < 16; ++q) v[q] = d2_lds[q * 64 + tid];

        int myidx = 1 << 20;
        #pragma unroll 1
        for (int k = 0; k < NCAND; ++k) {
            float bv = v[0];
            int bidx = tid;
            #pragma unroll
            for (int q = 1; q < 16; ++q) {
                float cv = v[q];
                int ci = q * 64 + tid;
                bool better = (cv < bv) || (cv == bv && ci < bidx);
                bv = better ? cv : bv;
                bidx = better ? ci : bidx;
            }
            #pragma unroll
            for (int st = 0; st < 6; ++st) {
                int msk = 1 << st;
                float ov = __shfl_xor(bv, msk, 64);
                int oi = __shfl_xor(bidx, msk, 64);
                bool better = (ov < bv) || (ov == bv && oi < bidx);
                bv = better ? ov : bv;
                bidx = better ? oi : bidx;
            }
            #pragma unroll
            for (int q = 0; q < 16; ++q)
                if (bidx == q * 64 + tid) v[q] = 3.4e38f;
            if (tid == k) myidx = bidx;
        }
        if (tid < NCAND) cand_lds[tid] = myidx;
    }
    __syncthreads();

    // ---- Phase C: np-exact rescore (R6's bit-exact op order) ----
    {
        const int wv = tid >> 6, lane = tid & 63;
        #pragma unroll 1
        for (int t = wv; t < NCAND; t += 4) {
            const int j = cand_lds[t];
            // s_c = 1/(1+expf(ps_c - pm_c)), lane = c
            float psc = psb[(long)j * C2 + lane];
            float e = expf(psc - pm_lds[lane]);
            float s_own = 1.0f / __fadd_rn(1.0f, e);
            sC[wv][lane] = s_own;
            LDS_FENCE();
            // w_d = sum_c s_c * A[c][d], ascending c, single fmaf acc; lane = d
            float wd = 0.f;
            #pragma unroll 4
            for (int c = 0; c < C2; ++c)
                wd = fmaf(sC[wv][c], A[c * C2 + lane], wd);
            // t_d = w_d * s_d (separate rounding)
            tC[wv][lane] = __fmul_rn(wd, s_own);
            LDS_FENCE();
            // numpy pairwise-8 partial sums
            if (lane < 8) {
                float r8 = tC[wv][lane];
                #pragma unroll
                for (int blk = 1; blk < 8; ++blk)
                    r8 = __fadd_rn(r8, tC[wv][8 * blk + lane]);
                r8C[wv][lane] = r8;
            }
            LDS_FENCE();
            if (lane == 0) {
                float dis2 = __fadd_rn(
                    __fadd_rn(__fadd_rn(r8C[wv][0], r8C[wv][1]),
                              __fadd_rn(r8C[wv][2], r8C[wv][3])),
                    __fadd_rn(__fadd_rn(r8C[wv][4], r8C[wv][5]),
                              __fadd_rn(r8C[wv][6], r8C[wv][7])));
                float disf = sqrtf(dis2);
                float ee = expf(disf);
                cdiff_lds[t] = 1.0f / __fadd_rn(1.0f, ee);  // sigmoid(-dis)
            }
            LDS_FENCE();
        }
    }
    __syncthreads();

    // ---- Final: top-16 over 24 exact diffs (desc, index asc), wave 0 ----
    if (tid < 64) {
        float myd = (tid < NCAND) ? cdiff_lds[tid] : -2.0f;
        int myj = (tid < NCAND) ? cand_lds[tid] : (1 << 20);

        const int obase = b * (NN * KK) + i * KK;    // index chunk (f32)
        const int vbase = 2 * NN * KK + obase;       // value chunk (f32)

        #pragma unroll 1
        for (int k = 0; k < KK; ++k) {
            float bd = myd;
            int bj = myj;
            #pragma unroll
            for (int st = 0; st < 6; ++st) {
                int msk = 1 << st;
                float od = __shfl_xor(bd, msk, 64);
                int oj = __shfl_xor(bj, msk, 64);
                bool better = (od > bd) || (od == bd && oj < bj);
                bd = better ? od : bd;
                bj = better ? oj : bj;
            }
            if (myj == bj) myd = -2.0f;              // candidate j's unique
            if (tid == 0) {
                out[obase + k] = (float)bj;
                out[vbase + k] = -bd;                // value = -topk(diff)
            }
        }
    }
}

extern "C" void kernel_launch(void* const* d_in, const int* in_sizes, int n_in,
                              void* d_out, int out_size, void* d_ws, size_t ws_size,
                              hipStream_t stream) {
    const float* X  = (const float*)d_in[0];
    const float* Wm = (const float*)d_in[1];
    const float* Ws = (const float*)d_in[2];
    const float* M  = (const float*)d_in[3];

    float* A  = (float*)d_ws;            // 4096 f   (16 KB)
    float* pm = A + C2 * C2;             // 131072 f (512 KB)
    float* ps = pm + 2 * NN * C2;        // 131072 f (512 KB)
    float* out = (float*)d_out;          // f32: [idx 32768][val 32768]

    hipLaunchKernelGGL(buildA, dim3(16), dim3(256), 0, stream, M, A);
    hipLaunchKernelGGL(proj, dim3(2 * NN), dim3(128), 0, stream,
                       X, Wm, Ws, pm, ps);
    hipLaunchKernelGGL(pair_topk, dim3(2 * NN), dim3(256), 0, stream,
                       pm, ps, M, A, out);
}

// Round 9
// 205.385 us; speedup vs baseline: 2.2243x; 1.7094x over previous
//
#include <hip/hip_runtime.h>
#include <hip/hip_bf16.h>
#include <math.h>

#define NN 1024
#define CC 128
#define C2 64
#define KK 16
#define NCAND 24

#if __has_builtin(__builtin_amdgcn_exp2f)
#define EXP2F(x) __builtin_amdgcn_exp2f(x)
#else
#define EXP2F(x) exp2f(x)
#endif
#define LOG2E 1.4426950408889634f

typedef short short8 __attribute__((ext_vector_type(8)));
typedef float f32x4  __attribute__((ext_vector_type(4)));

__device__ __forceinline__ float fast_rcp(float x) {
    return __builtin_amdgcn_rcpf(x);
}
__device__ __forceinline__ unsigned short f2bf(float x) {   // RNE f32->bf16
    unsigned int u = __float_as_uint(x);
    unsigned int r = (u + 0x7FFFu + ((u >> 16) & 1u)) >> 16;
    return (unsigned short)r;
}
__device__ __forceinline__ float bf2f(unsigned short h) {
    return __uint_as_float(((unsigned int)h) << 16);
}

// LDS write->read visibility within one wave (lockstep): wait LDS ops, pin order.
#define LDS_FENCE() do { \
    asm volatile("s_waitcnt lgkmcnt(0)" ::: "memory"); \
    __builtin_amdgcn_sched_barrier(0); } while (0)

// ---------------- K0: A = M^T M, f32, ascending-r fmaf chain (np-exact) ----
__global__ __launch_bounds__(256) void buildA(const float* __restrict__ M,
                                              float* __restrict__ A) {
    const int e = blockIdx.x * 256 + threadIdx.x;    // 4096 entries
    const int c = e >> 6, d = e & 63;
    float acc = 0.f;
    #pragma unroll 8
    for (int r = 0; r < C2; ++r)
        acc = fmaf(M[r * C2 + c], M[r * C2 + d], acc);
    A[e] = acc;                                      // A[c][d] row-major
}

// ---------------- K1: projections + logmap, f32 (np-exact) -----------------
__global__ __launch_bounds__(128) void proj(
        const float* __restrict__ X,
        const float* __restrict__ Wm,
        const float* __restrict__ Ws,
        float* __restrict__ pm,
        float* __restrict__ ps) {
    const int bn = blockIdx.x;           // b*1024 + n
    const int b  = bn >> 10;
    const int n  = bn & (NN - 1);
    const int t  = threadIdx.x;          // 0..127

    __shared__ float xv[CC];
    xv[t] = X[b * CC * NN + t * NN + n];
    __syncthreads();

    const int d = t & (C2 - 1);
    const float* wr = ((t < C2) ? Wm : Ws) + d * CC;
    float acc = 0.f;
    #pragma unroll
    for (int c = 0; c < CC; ++c)
        acc = fmaf(wr[c], xv[c], acc);   // sequential k-order, single acc

    float a = __fadd_rn(fabsf(acc), 1e-10f);
    float l = logf(a);
    float r = (acc > 0.f) ? l : ((acc < 0.f) ? -l : 0.f);
    ((t < C2) ? pm : ps)[bn * C2 + d] = r;
}

// ---------------- K2: MFMA candidate pass + np-exact re-rank ---------------
// One block per (b,i), 256 threads = 4 waves.
//  A: dis2 proxy via bf16 3-term-split MFMA: U = M.S, dis2[j] = sum_r U^2.
//     Per wave: 16 j-tiles (16 j each); lane computes exactly its own
//     B-fragment sigmoids (j = lane&15, c = (lane>>4)*8 + kt*32 .. +8).
//  B: wave0 picks 24 smallest-dis2 candidates (superset of np top-16)
//  C: 4 waves rescore candidates with R6's EXACT np-f32 op sequence
//  F: wave0 top-16 on exact diff (desc, index asc) -> out
__global__ __launch_bounds__(256, 2) void pair_topk(
        const float* __restrict__ pm,
        const float* __restrict__ ps,
        const float* __restrict__ Mf,
        const float* __restrict__ A,
        float* __restrict__ out) {
    const int bi  = blockIdx.x;          // b*1024 + i
    const int b   = bi >> 10;
    const int i   = bi & (NN - 1);
    const int tid = threadIdx.x;
    const int lane = tid & 63;
    const int wv   = tid >> 6;           // wave 0..3
    const int g    = lane >> 4;          // k-group 0..3
    const int lj   = lane & 15;          // col within j-tile / row within r-tile

    __shared__ float pm_lds[C2];
    __shared__ float d2_lds[NN];
    __shared__ int   cand_lds[NCAND];
    __shared__ float cdiff_lds[NCAND];
    __shared__ float sC[4][C2];
    __shared__ float tC[4][C2];
    __shared__ float r8C[4][8];

    if (tid < C2) pm_lds[tid] = pm[bi * C2 + tid];   // exact f32 pm row
    __syncthreads();

    const float* psb = ps + b * NN * C2;

    // ---- pm slice this lane needs, into registers ----
    float pmr[2][8];
    #pragma unroll
    for (int kt = 0; kt < 2; ++kt) {
        const float4 a0 = *(const float4*)&pm_lds[kt * 32 + g * 8];
        const float4 a1 = *(const float4*)&pm_lds[kt * 32 + g * 8 + 4];
        pmr[kt][0] = a0.x; pmr[kt][1] = a0.y; pmr[kt][2] = a0.z; pmr[kt][3] = a0.w;
        pmr[kt][4] = a1.x; pmr[kt][5] = a1.y; pmr[kt][6] = a1.z; pmr[kt][7] = a1.w;
    }

    // ---- A-fragments: M rows hi/lo bf16 (per-lane, held in VGPRs) ----
    short8 ahi[4][2], alo[4][2];
    #pragma unroll
    for (int rt = 0; rt < 4; ++rt) {
        #pragma unroll
        for (int kt = 0; kt < 2; ++kt) {
            const float* mrow = Mf + (rt * 16 + lj) * C2 + kt * 32 + g * 8;
            const float4 m0 = *(const float4*)mrow;
            const float4 m1 = *(const float4*)(mrow + 4);
            float mv[8] = {m0.x, m0.y, m0.z, m0.w, m1.x, m1.y, m1.z, m1.w};
            #pragma unroll
            for (int e = 0; e < 8; ++e) {
                unsigned short h = f2bf(mv[e]);
                ahi[rt][kt][e] = (short)h;
                alo[rt][kt][e] = (short)f2bf(mv[e] - bf2f(h));
            }
        }
    }

    // ---- Phase A: 16 j-tiles per wave ----
    #pragma unroll 1
    for (int t = 0; t < 16; ++t) {
        const int jt = wv * 16 + t;
        const int j  = jt * 16 + lj;
        const float* pj = psb + (long)j * C2;

        f32x4 acc0 = {0.f,0.f,0.f,0.f}, acc1 = {0.f,0.f,0.f,0.f};
        f32x4 acc2 = {0.f,0.f,0.f,0.f}, acc3 = {0.f,0.f,0.f,0.f};

        #pragma unroll
        for (int kt = 0; kt < 2; ++kt) {
            const float4 v0 = *(const float4*)(pj + kt * 32 + g * 8);
            const float4 v1 = *(const float4*)(pj + kt * 32 + g * 8 + 4);
            float sv[8];
            sv[0] = fast_rcp(1.0f + EXP2F((v0.x - pmr[kt][0]) * LOG2E));
            sv[1] = fast_rcp(1.0f + EXP2F((v0.y - pmr[kt][1]) * LOG2E));
            sv[2] = fast_rcp(1.0f + EXP2F((v0.z - pmr[kt][2]) * LOG2E));
            sv[3] = fast_rcp(1.0f + EXP2F((v0.w - pmr[kt][3]) * LOG2E));
            sv[4] = fast_rcp(1.0f + EXP2F((v1.x - pmr[kt][4]) * LOG2E));
            sv[5] = fast_rcp(1.0f + EXP2F((v1.y - pmr[kt][5]) * LOG2E));
            sv[6] = fast_rcp(1.0f + EXP2F((v1.z - pmr[kt][6]) * LOG2E));
            sv[7] = fast_rcp(1.0f + EXP2F((v1.w - pmr[kt][7]) * LOG2E));

            short8 bhi, blo;
            #pragma unroll
            for (int e = 0; e < 8; ++e) {
                unsigned short h = f2bf(sv[e]);
                bhi[e] = (short)h;
                blo[e] = (short)f2bf(sv[e] - bf2f(h));
            }

            acc0 = __builtin_amdgcn_mfma_f32_16x16x32_bf16(ahi[0][kt], bhi, acc0, 0, 0, 0);
            acc0 = __builtin_amdgcn_mfma_f32_16x16x32_bf16(ahi[0][kt], blo, acc0, 0, 0, 0);
            acc0 = __builtin_amdgcn_mfma_f32_16x16x32_bf16(alo[0][kt], bhi, acc0, 0, 0, 0);
            acc1 = __builtin_amdgcn_mfma_f32_16x16x32_bf16(ahi[1][kt], bhi, acc1, 0, 0, 0);
            acc1 = __builtin_amdgcn_mfma_f32_16x16x32_bf16(ahi[1][kt], blo, acc1, 0, 0, 0);
            acc1 = __builtin_amdgcn_mfma_f32_16x16x32_bf16(alo[1][kt], bhi, acc1, 0, 0, 0);
            acc2 = __builtin_amdgcn_mfma_f32_16x16x32_bf16(ahi[2][kt], bhi, acc2, 0, 0, 0);
            acc2 = __builtin_amdgcn_mfma_f32_16x16x32_bf16(ahi[2][kt], blo, acc2, 0, 0, 0);
            acc2 = __builtin_amdgcn_mfma_f32_16x16x32_bf16(alo[2][kt], bhi, acc2, 0, 0, 0);
            acc3 = __builtin_amdgcn_mfma_f32_16x16x32_bf16(ahi[3][kt], bhi, acc3, 0, 0, 0);
            acc3 = __builtin_amdgcn_mfma_f32_16x16x32_bf16(ahi[3][kt], blo, acc3, 0, 0, 0);
            acc3 = __builtin_amdgcn_mfma_f32_16x16x32_bf16(alo[3][kt], bhi, acc3, 0, 0, 0);
        }

        // dis2[j] = sum over all 64 rows of U^2
        float sq = 0.f;
        #pragma unroll
        for (int e = 0; e < 4; ++e) {
            sq = fmaf(acc0[e], acc0[e], sq);
            sq = fmaf(acc1[e], acc1[e], sq);
            sq = fmaf(acc2[e], acc2[e], sq);
            sq = fmaf(acc3[e], acc3[e], sq);
        }
        sq += __shfl_xor(sq, 16, 64);
        sq += __shfl_xor(sq, 32, 64);
        if (lane < 16) d2_lds[jt * 16 + lane] = sq;
    }
    __syncthreads();

    // ---- Phase B: 24 smallest-dis2 candidate indices (wave 0) ----
    if (tid < 64) {
        float v[16];
        #pragma unroll
        for (int q = 0; q < 16; ++q) v[q] = d2_lds[q * 64 + tid];

        int myidx = 1 << 20;
        #pragma unroll 1
        for (int k = 0; k < NCAND; ++k) {
            float bv = v[0];
            int bidx = tid;
            #pragma unroll
            for (int q = 1; q < 16; ++q) {
                float cv = v[q];
                int ci = q * 64 + tid;
                bool better = (cv < bv) || (cv == bv && ci < bidx);
                bv = better ? cv : bv;
                bidx = better ? ci : bidx;
            }
            #pragma unroll
            for (int st = 0; st < 6; ++st) {
                int msk = 1 << st;
                float ov = __shfl_xor(bv, msk, 64);
                int oi = __shfl_xor(bidx, msk, 64);
                bool better = (ov < bv) || (ov == bv && oi < bidx);
                bv = better ? ov : bv;
                bidx = better ? oi : bidx;
            }
            #pragma unroll
            for (int q = 0; q < 16; ++q)
                if (bidx == q * 64 + tid) v[q] = 3.4e38f;
            if (tid == k) myidx = bidx;
        }
        if (tid < NCAND) cand_lds[tid] = myidx;
    }
    __syncthreads();

    // ---- Phase C: np-exact rescore (R6's bit-exact op order) ----
    {
        #pragma unroll 1
        for (int t = wv; t < NCAND; t += 4) {
            const int j = cand_lds[t];
            // s_c = 1/(1+expf(ps_c - pm_c)), lane = c
            float psc = psb[(long)j * C2 + lane];
            float e = expf(psc - pm_lds[lane]);
            float s_own = 1.0f / __fadd_rn(1.0f, e);
            sC[wv][lane] = s_own;
            LDS_FENCE();
            // w_d = sum_c s_c * A[c][d], ascending c, single fmaf acc; lane = d
            float wd = 0.f;
            #pragma unroll 4
            for (int c = 0; c < C2; ++c)
                wd = fmaf(sC[wv][c], A[c * C2 + lane], wd);
            // t_d = w_d * s_d (separate rounding)
            tC[wv][lane] = __fmul_rn(wd, s_own);
            LDS_FENCE();
            // numpy pairwise-8 partial sums
            if (lane < 8) {
                float r8 = tC[wv][lane];
                #pragma unroll
                for (int blk = 1; blk < 8; ++blk)
                    r8 = __fadd_rn(r8, tC[wv][8 * blk + lane]);
                r8C[wv][lane] = r8;
            }
            LDS_FENCE();
            if (lane == 0) {
                float dis2 = __fadd_rn(
                    __fadd_rn(__fadd_rn(r8C[wv][0], r8C[wv][1]),
                              __fadd_rn(r8C[wv][2], r8C[wv][3])),
                    __fadd_rn(__fadd_rn(r8C[wv][4], r8C[wv][5]),
                              __fadd_rn(r8C[wv][6], r8C[wv][7])));
                float disf = sqrtf(dis2);
                float ee = expf(disf);
                cdiff_lds[t] = 1.0f / __fadd_rn(1.0f, ee);  // sigmoid(-dis)
            }
            LDS_FENCE();
        }
    }
    __syncthreads();

    // ---- Final: top-16 over 24 exact diffs (desc, index asc), wave 0 ----
    if (tid < 64) {
        float myd = (tid < NCAND) ? cdiff_lds[tid] : -2.0f;
        int myj = (tid < NCAND) ? cand_lds[tid] : (1 << 20);

        const int obase = b * (NN * KK) + i * KK;    // index chunk (f32)
        const int vbase = 2 * NN * KK + obase;       // value chunk (f32)

        #pragma unroll 1
        for (int k = 0; k < KK; ++k) {
            float bd = myd;
            int bj = myj;
            #pragma unroll
            for (int st = 0; st < 6; ++st) {
                int msk = 1 << st;
                float od = __shfl_xor(bd, msk, 64);
                int oj = __shfl_xor(bj, msk, 64);
                bool better = (od > bd) || (od == bd && oj < bj);
                bd = better ? od : bd;
                bj = better ? oj : bj;
            }
            if (myj == bj) myd = -2.0f;              // candidate j's unique
            if (tid == 0) {
                out[obase + k] = (float)bj;
                out[vbase + k] = -bd;                // value = -topk(diff)
            }
        }
    }
}

extern "C" void kernel_launch(void* const* d_in, const int* in_sizes, int n_in,
                              void* d_out, int out_size, void* d_ws, size_t ws_size,
                              hipStream_t stream) {
    const float* X  = (const float*)d_in[0];
    const float* Wm = (const float*)d_in[1];
    const float* Ws = (const float*)d_in[2];
    const float* M  = (const float*)d_in[3];

    float* A  = (float*)d_ws;            // 4096 f   (16 KB)
    float* pm = A + C2 * C2;             // 131072 f (512 KB)
    float* ps = pm + 2 * NN * C2;        // 131072 f (512 KB)
    float* out = (float*)d_out;          // f32: [idx 32768][val 32768]

    hipLaunchKernelGGL(buildA, dim3(16), dim3(256), 0, stream, M, A);
    hipLaunchKernelGGL(proj, dim3(2 * NN), dim3(128), 0, stream,
                       X, Wm, Ws, pm, ps);
    hipLaunchKernelGGL(pair_topk, dim3(2 * NN), dim3(256), 0, stream,
                       pm, ps, M, A, out);
}

// Round 10
// 135.549 us; speedup vs baseline: 3.3703x; 1.5152x over previous
//
#include <hip/hip_runtime.h>
#include <hip/hip_bf16.h>
#include <math.h>

#define NN 1024
#define CC 128
#define C2 64
#define KK 16
#define NCAND 24

#if __has_builtin(__builtin_amdgcn_exp2f)
#define EXP2F(x) __builtin_amdgcn_exp2f(x)
#else
#define EXP2F(x) exp2f(x)
#endif
#define LOG2E 1.4426950408889634f

typedef short short8 __attribute__((ext_vector_type(8)));
typedef float f32x4  __attribute__((ext_vector_type(4)));
typedef int   int4v  __attribute__((ext_vector_type(4)));
typedef unsigned int uint;

__device__ __forceinline__ float fast_rcp(float x) {
    return __builtin_amdgcn_rcpf(x);
}
__device__ __forceinline__ unsigned short f2bf(float x) {   // RNE f32->bf16
    unsigned int u = __float_as_uint(x);
    unsigned int r = (u + 0x7FFFu + ((u >> 16) & 1u)) >> 16;
    return (unsigned short)r;
}
__device__ __forceinline__ float bf2f(unsigned short h) {
    return __uint_as_float(((unsigned int)h) << 16);
}

// In-wave LDS write->read visibility: wait LDS ops, pin compiler order.
#define LDS_FENCE() do { \
    asm volatile("s_waitcnt lgkmcnt(0)" ::: "memory"); \
    __builtin_amdgcn_sched_barrier(0); } while (0)

// ---------------- K0: A = M^T M, f32, ascending-r fmaf chain (np-exact) ----
__global__ __launch_bounds__(256) void buildA(const float* __restrict__ M,
                                              float* __restrict__ A) {
    const int e = blockIdx.x * 256 + threadIdx.x;    // 4096 entries
    const int c = e >> 6, d = e & 63;
    float acc = 0.f;
    #pragma unroll 8
    for (int r = 0; r < C2; ++r)
        acc = fmaf(M[r * C2 + c], M[r * C2 + d], acc);
    A[e] = acc;                                      // A[c][d] row-major
}

// ---------------- K1: projections + logmap, f32 (np-exact) + psE -----------
__global__ __launch_bounds__(128) void proj(
        const float* __restrict__ X,
        const float* __restrict__ Wm,
        const float* __restrict__ Ws,
        float* __restrict__ pm,
        float* __restrict__ ps,
        float* __restrict__ psE) {
    const int bn = blockIdx.x;           // b*1024 + n
    const int b  = bn >> 10;
    const int n  = bn & (NN - 1);
    const int t  = threadIdx.x;          // 0..127

    __shared__ float xv[CC];
    xv[t] = X[b * CC * NN + t * NN + n];
    __syncthreads();

    const int d = t & (C2 - 1);
    const float* wr = ((t < C2) ? Wm : Ws) + d * CC;
    float acc = 0.f;
    #pragma unroll
    for (int c = 0; c < CC; ++c)
        acc = fmaf(wr[c], xv[c], acc);   // sequential k-order, single acc

    float a = __fadd_rn(fabsf(acc), 1e-10f);
    float l = logf(a);
    float r = (acc > 0.f) ? l : ((acc < 0.f) ? -l : 0.f);
    if (t < C2) {
        pm[bn * C2 + d] = r;
    } else {
        ps[bn * C2 + d] = r;
        psE[bn * C2 + d] = EXP2F(r * LOG2E);   // e^ps (proxy pass only)
    }
}

// ---------------- K2: per-wave row pipeline (NO block barriers) ------------
__global__ __launch_bounds__(256, 2) void pair_topk(
        const float* __restrict__ pm,
        const float* __restrict__ ps,
        const float* __restrict__ psE,
        const float* __restrict__ Mf,
        const float* __restrict__ A,
        float* __restrict__ out) {
    const int tid  = threadIdx.x;
    const int wv   = tid >> 6;
    const int lane = tid & 63;
    const int g    = lane >> 4;          // k-group 0..3
    const int lj   = lane & 15;          // col (B) / row (A) within tile

    const int bi = blockIdx.x * 4 + wv;  // row 0..2047
    const int b  = bi >> 10;
    const int i  = bi & (NN - 1);

    __shared__ float d2w[4][NN];         // per-wave dis2 (16 KB)
    __shared__ float sC[4][C2];
    __shared__ float tC[4][C2];
    __shared__ float r8C[4][8];
    __shared__ float cdiffL[4][NCAND];

    const float* psb  = ps  + b * NN * C2;
    const float* psEb = psE + b * NN * C2;

    const float pm_own = pm[bi * C2 + lane];         // exact (phase C)

    float pmEf[2][8];
    #pragma unroll
    for (int kt = 0; kt < 2; ++kt) {
        const float4 a0 = *(const float4*)(pm + bi * C2 + kt * 32 + g * 8);
        const float4 a1 = *(const float4*)(pm + bi * C2 + kt * 32 + g * 8 + 4);
        pmEf[kt][0] = EXP2F(a0.x * LOG2E); pmEf[kt][1] = EXP2F(a0.y * LOG2E);
        pmEf[kt][2] = EXP2F(a0.z * LOG2E); pmEf[kt][3] = EXP2F(a0.w * LOG2E);
        pmEf[kt][4] = EXP2F(a1.x * LOG2E); pmEf[kt][5] = EXP2F(a1.y * LOG2E);
        pmEf[kt][6] = EXP2F(a1.z * LOG2E); pmEf[kt][7] = EXP2F(a1.w * LOG2E);
    }

    // ---- Phase A (scoped so M fragments die before phase C) ----
    {
        short8 ahi[4][2], alo[4][2];     // M rows hi/lo bf16 (RNE, once)
        #pragma unroll
        for (int rt = 0; rt < 4; ++rt) {
            #pragma unroll
            for (int kt = 0; kt < 2; ++kt) {
                const float* mrow = Mf + (rt * 16 + lj) * C2 + kt * 32 + g * 8;
                const float4 m0 = *(const float4*)mrow;
                const float4 m1 = *(const float4*)(mrow + 4);
                float mv[8] = {m0.x, m0.y, m0.z, m0.w, m1.x, m1.y, m1.z, m1.w};
                #pragma unroll
                for (int e = 0; e < 8; ++e) {
                    unsigned short h = f2bf(mv[e]);
                    ahi[rt][kt][e] = (short)h;
                    alo[rt][kt][e] = (short)f2bf(mv[e] - bf2f(h));
                }
            }
        }

        #pragma unroll 2
        for (int jt = 0; jt < 64; ++jt) {
            const int j = jt * 16 + lj;
            const float* pjE = psEb + (long)j * C2;

            f32x4 acc0 = {0.f,0.f,0.f,0.f}, acc1 = {0.f,0.f,0.f,0.f};
            f32x4 acc2 = {0.f,0.f,0.f,0.f}, acc3 = {0.f,0.f,0.f,0.f};

            #pragma unroll
            for (int kt = 0; kt < 2; ++kt) {
                const float4 y0 = *(const float4*)(pjE + kt * 32 + g * 8);
                const float4 y1 = *(const float4*)(pjE + kt * 32 + g * 8 + 4);
                float s0 = pmEf[kt][0] * fast_rcp(pmEf[kt][0] + y0.x);
                float s1 = pmEf[kt][1] * fast_rcp(pmEf[kt][1] + y0.y);
                float s2 = pmEf[kt][2] * fast_rcp(pmEf[kt][2] + y0.z);
                float s3 = pmEf[kt][3] * fast_rcp(pmEf[kt][3] + y0.w);
                float s4 = pmEf[kt][4] * fast_rcp(pmEf[kt][4] + y1.x);
                float s5 = pmEf[kt][5] * fast_rcp(pmEf[kt][5] + y1.y);
                float s6 = pmEf[kt][6] * fast_rcp(pmEf[kt][6] + y1.z);
                float s7 = pmEf[kt][7] * fast_rcp(pmEf[kt][7] + y1.w);
                uint u0 = __float_as_uint(s0), u1 = __float_as_uint(s1);
                uint u2 = __float_as_uint(s2), u3 = __float_as_uint(s3);
                uint u4 = __float_as_uint(s4), u5 = __float_as_uint(s5);
                uint u6 = __float_as_uint(s6), u7 = __float_as_uint(s7);
                uint l0 = __float_as_uint(s0 - __uint_as_float(u0 & 0xFFFF0000u));
                uint l1 = __float_as_uint(s1 - __uint_as_float(u1 & 0xFFFF0000u));
                uint l2 = __float_as_uint(s2 - __uint_as_float(u2 & 0xFFFF0000u));
                uint l3 = __float_as_uint(s3 - __uint_as_float(u3 & 0xFFFF0000u));
                uint l4 = __float_as_uint(s4 - __uint_as_float(u4 & 0xFFFF0000u));
                uint l5 = __float_as_uint(s5 - __uint_as_float(u5 & 0xFFFF0000u));
                uint l6 = __float_as_uint(s6 - __uint_as_float(u6 & 0xFFFF0000u));
                uint l7 = __float_as_uint(s7 - __uint_as_float(u7 & 0xFFFF0000u));
                int4v hiv = { (int)__builtin_amdgcn_perm(u1, u0, 0x07060302u),
                              (int)__builtin_amdgcn_perm(u3, u2, 0x07060302u),
                              (int)__builtin_amdgcn_perm(u5, u4, 0x07060302u),
                              (int)__builtin_amdgcn_perm(u7, u6, 0x07060302u) };
                int4v lov = { (int)__builtin_amdgcn_perm(l1, l0, 0x07060302u),
                              (int)__builtin_amdgcn_perm(l3, l2, 0x07060302u),
                              (int)__builtin_amdgcn_perm(l5, l4, 0x07060302u),
                              (int)__builtin_amdgcn_perm(l7, l6, 0x07060302u) };
                short8 bhi = __builtin_bit_cast(short8, hiv);
                short8 blo = __builtin_bit_cast(short8, lov);

                acc0 = __builtin_amdgcn_mfma_f32_16x16x32_bf16(ahi[0][kt], bhi, acc0, 0, 0, 0);
                acc0 = __builtin_amdgcn_mfma_f32_16x16x32_bf16(ahi[0][kt], blo, acc0, 0, 0, 0);
                acc0 = __builtin_amdgcn_mfma_f32_16x16x32_bf16(alo[0][kt], bhi, acc0, 0, 0, 0);
                acc1 = __builtin_amdgcn_mfma_f32_16x16x32_bf16(ahi[1][kt], bhi, acc1, 0, 0, 0);
                acc1 = __builtin_amdgcn_mfma_f32_16x16x32_bf16(ahi[1][kt], blo, acc1, 0, 0, 0);
                acc1 = __builtin_amdgcn_mfma_f32_16x16x32_bf16(alo[1][kt], bhi, acc1, 0, 0, 0);
                acc2 = __builtin_amdgcn_mfma_f32_16x16x32_bf16(ahi[2][kt], bhi, acc2, 0, 0, 0);
                acc2 = __builtin_amdgcn_mfma_f32_16x16x32_bf16(ahi[2][kt], blo, acc2, 0, 0, 0);
                acc2 = __builtin_amdgcn_mfma_f32_16x16x32_bf16(alo[2][kt], bhi, acc2, 0, 0, 0);
                acc3 = __builtin_amdgcn_mfma_f32_16x16x32_bf16(ahi[3][kt], bhi, acc3, 0, 0, 0);
                acc3 = __builtin_amdgcn_mfma_f32_16x16x32_bf16(ahi[3][kt], blo, acc3, 0, 0, 0);
                acc3 = __builtin_amdgcn_mfma_f32_16x16x32_bf16(alo[3][kt], bhi, acc3, 0, 0, 0);
            }

            float sq = 0.f;
            #pragma unroll
            for (int e = 0; e < 4; ++e) {
                sq = fmaf(acc0[e], acc0[e], sq);
                sq = fmaf(acc1[e], acc1[e], sq);
                sq = fmaf(acc2[e], acc2[e], sq);
                sq = fmaf(acc3[e], acc3[e], sq);
            }
            sq += __shfl_xor(sq, 16, 64);
            sq += __shfl_xor(sq, 32, 64);
            if (lane < 16) d2w[wv][jt * 16 + lane] = sq;
        }
    }
    LDS_FENCE();

    // ---- Phase B: 24 smallest proxy-dis2 candidates (per wave) ----
    float v[16];
    #pragma unroll
    for (int q = 0; q < 16; ++q) v[q] = d2w[wv][q * 64 + lane];

    int myCand = 1 << 20;
    #pragma unroll 1
    for (int k = 0; k < NCAND; ++k) {
        float bv = v[0];
        int bidx = lane;
        #pragma unroll
        for (int q = 1; q < 16; ++q) {
            float cv = v[q];
            int ci = q * 64 + lane;
            bool better = (cv < bv) || (cv == bv && ci < bidx);
            bv = better ? cv : bv;
            bidx = better ? ci : bidx;
        }
        #pragma unroll
        for (int st = 0; st < 6; ++st) {
            int msk = 1 << st;
            float ov = __shfl_xor(bv, msk, 64);
            int oi = __shfl_xor(bidx, msk, 64);
            bool better = (ov < bv) || (ov == bv && oi < bidx);
            bv = better ? ov : bv;
            bidx = better ? oi : bidx;
        }
        #pragma unroll
        for (int q = 0; q < 16; ++q)
            if (bidx == q * 64 + lane) v[q] = 3.4e38f;
        if (lane == k) myCand = bidx;
    }

    // ---- Phase C: np-exact rescore (R6 bit-exact); A columns in regs ----
    float Acol[C2];
    #pragma unroll
    for (int c = 0; c < C2; ++c) Acol[c] = A[c * C2 + lane];

    #pragma unroll 1
    for (int t = 0; t < NCAND; ++t) {
        const int j = __shfl(myCand, t, 64);
        float psc = psb[(long)j * C2 + lane];
        float e = expf(psc - pm_own);
        float s_own = 1.0f / __fadd_rn(1.0f, e);     // sigmoid(pm-ps)
        sC[wv][lane] = s_own;
        LDS_FENCE();
        float wd = 0.f;
        #pragma unroll
        for (int c = 0; c < C2; ++c)                 // ascending c, single acc
            wd = fmaf(sC[wv][c], Acol[c], wd);
        tC[wv][lane] = __fmul_rn(wd, s_own);
        LDS_FENCE();
        if (lane < 8) {                              // numpy pairwise-8
            float r8 = tC[wv][lane];
            #pragma unroll
            for (int blk = 1; blk < 8; ++blk)
                r8 = __fadd_rn(r8, tC[wv][8 * blk + lane]);
            r8C[wv][lane] = r8;
        }
        LDS_FENCE();
        if (lane == 0) {
            float dis2 = __fadd_rn(
                __fadd_rn(__fadd_rn(r8C[wv][0], r8C[wv][1]),
                          __fadd_rn(r8C[wv][2], r8C[wv][3])),
                __fadd_rn(__fadd_rn(r8C[wv][4], r8C[wv][5]),
                          __fadd_rn(r8C[wv][6], r8C[wv][7])));
            float disf = sqrtf(dis2);
            float ee = expf(disf);
            cdiffL[wv][t] = 1.0f / __fadd_rn(1.0f, ee);  // sigmoid(-dis)
        }
        LDS_FENCE();
    }

    // ---- Final: per-wave top-16 over 24 exact diffs (desc, index asc) ----
    float myd = (lane < NCAND) ? cdiffL[wv][lane] : -2.0f;
    int myj = (lane < NCAND) ? myCand : (1 << 20);

    const int obase = b * (NN * KK) + i * KK;        // index chunk (f32)
    const int vbase = 2 * NN * KK + obase;           // value chunk (f32)

    #pragma unroll 1
    for (int k = 0; k < KK; ++k) {
        float bd = myd;
        int bj = myj;
        #pragma unroll
        for (int st = 0; st < 6; ++st) {
            int msk = 1 << st;
            float od = __shfl_xor(bd, msk, 64);
            int oj = __shfl_xor(bj, msk, 64);
            bool better = (od > bd) || (od == bd && oj < bj);
            bd = better ? od : bd;
            bj = better ? oj : bj;
        }
        if (myj == bj) myd = -2.0f;                  // candidate j's unique
        if (lane == 0) {
            out[obase + k] = (float)bj;
            out[vbase + k] = -bd;                    // value = -topk(diff)
        }
    }
}

extern "C" void kernel_launch(void* const* d_in, const int* in_sizes, int n_in,
                              void* d_out, int out_size, void* d_ws, size_t ws_size,
                              hipStream_t stream) {
    const float* X  = (const float*)d_in[0];
    const float* Wm = (const float*)d_in[1];
    const float* Ws = (const float*)d_in[2];
    const float* M  = (const float*)d_in[3];

    float* A   = (float*)d_ws;           // 4096 f   (16 KB)
    float* pm  = A + C2 * C2;            // 131072 f (512 KB)
    float* ps  = pm + 2 * NN * C2;       // 131072 f (512 KB)
    float* psE = ps + 2 * NN * C2;       // 131072 f (512 KB)  total ~1.52 MB
    float* out = (float*)d_out;          // f32: [idx 32768][val 32768]

    hipLaunchKernelGGL(buildA, dim3(16), dim3(256), 0, stream, M, A);
    hipLaunchKernelGGL(proj, dim3(2 * NN), dim3(128), 0, stream,
                       X, Wm, Ws, pm, ps, psE);
    hipLaunchKernelGGL(pair_topk, dim3(512), dim3(256), 0, stream,
                       pm, ps, psE, M, A, out);
}